// Round 5
// baseline (226.380 us; speedup 1.0000x reference)
//
#include <hip/hip_runtime.h>
#include <math.h>

#define DM 512
#define NN 512
#define SCALE 651.8986469044033f   // 4096/(2*pi), rounds to same f32 as reference
#define MAGIC 12582912.0f          // 1.5 * 2^23: fma+magic => RNE integer in low mantissa
#define NL 56                      // d-iters via LDS LUT; remaining 8 via v_sin/v_cos

__device__ __forceinline__ unsigned bf16rne(float f) {
    unsigned u = __float_as_uint(f);
    return (u + 0x7fffu + ((u >> 16) & 1u)) >> 16;
}

// ---------------------------------------------------------------------------
// kprep: 192 blocks = 3 phases x 64 tiles; each block does ONE 64x64 LDS-tile
// transpose with a single __syncthreads. All global reads/writes coalesced.
//   phase 0: packAB[d][n].xy = {SCALE/(1+|W|), B*SCALE + MAGIC}
//   phase 1: packAB[d][n].zw = {attn_cos, attn_sin}
//   phase 2: projT[n][d]     = {proj_cos_w[d][n], proj_sin_w[d][n]}
// ---------------------------------------------------------------------------
__global__ __launch_bounds__(256) void kprep(
    const float* __restrict__ W, const float* __restrict__ B,
    const float* __restrict__ AC, const float* __restrict__ AS,
    const float* __restrict__ PC, const float* __restrict__ PS,
    float2* __restrict__ packAB, float2* __restrict__ projT)
{
    __shared__ float2 tile[64][65];
    const int tid = threadIdx.x;
    const int tx = tid & 63, ty = tid >> 6;
    const int phase = blockIdx.x >> 6;       // 0..2
    const int tl = blockIdx.x & 63;
    const int r0 = (tl >> 3) * 64;           // source row tile
    const int c0 = (tl & 7) * 64;            // source col tile

    if (phase == 0) {
#pragma unroll
        for (int p = 0; p < 16; ++p) {
            int r = p * 4 + ty;
            float w = W[(r0 + r) * DM + c0 + tx];
            float b = B[(r0 + r) * DM + c0 + tx];
            tile[r][tx] = make_float2(SCALE / (1.0f + fabsf(w)),
                                      fmaf(b, SCALE, MAGIC));
        }
        __syncthreads();
#pragma unroll
        for (int p = 0; p < 16; ++p) {
            int c = p * 4 + ty;
            packAB[((c0 + c) * NN + r0 + tx) * 2] = tile[tx][c];
        }
    } else if (phase == 1) {
#pragma unroll
        for (int p = 0; p < 16; ++p) {
            int r = p * 4 + ty;
            tile[r][tx] = make_float2(AC[(r0 + r) * DM + c0 + tx],
                                      AS[(r0 + r) * DM + c0 + tx]);
        }
        __syncthreads();
#pragma unroll
        for (int p = 0; p < 16; ++p) {
            int c = p * 4 + ty;
            packAB[((c0 + c) * NN + r0 + tx) * 2 + 1] = tile[tx][c];
        }
    } else {
        // PC/PS are [d][n]: r0 = d-rows, c0 = n-cols (square, same tiling)
#pragma unroll
        for (int p = 0; p < 16; ++p) {
            int r = p * 4 + ty;
            tile[r][tx] = make_float2(PC[(r0 + r) * NN + c0 + tx],
                                      PS[(r0 + r) * NN + c0 + tx]);
        }
        __syncthreads();
#pragma unroll
        for (int p = 0; p < 16; ++p) {
            int c = p * 4 + ty;
            projT[(c0 + c) * DM + r0 + tx] = tile[tx][c];
        }
    }
}

// ---------------------------------------------------------------------------
// kmain: cos_sum/sin_sum over d. Block = 512 thr = 8 waves; block owns
// (8 tokens) x (64 neurons); wave owns a 64-wide d-slice; lane = neuron.
// Grid = 128 token-tiles x 8 ng. First NL d-iters: LDS-LUT gather, index =
// RNE(theta*SCALE) in low mantissa bits via the 1.5*2^23 magic, & 4095.
// Last 64-NL iters: v_sin/v_cos (trans pipe) with IDENTICAL quantization:
// J = f - MAGIC exactly, phase = fract(J/4096) revolutions.
// Cross-wave d-reduction via ds_add_f32 atomics.
// ---------------------------------------------------------------------------
__global__ __launch_bounds__(512) void kmain(
    const float* __restrict__ x,
    const float* __restrict__ sinT, const float* __restrict__ cosT,
    const float4* __restrict__ packAB,
    float2* __restrict__ pairs)
{
    __shared__ unsigned lut[4096];   // 16 KB: sin bf16 lo | cos bf16 hi
    __shared__ float2 accL[8][64];   // 4 KB accumulator

    const int tid  = threadIdx.x;
    const int bid  = blockIdx.x;     // 1024 = 128 tiles * 8 ng
    const int tile = bid >> 3, ng = bid & 7;
    const int lane = tid & 63;
    const int wv   = __builtin_amdgcn_readfirstlane(tid >> 6);
    const int t0   = tile * 8;

#pragma unroll
    for (int j = 0; j < 8; ++j) {
        int k = tid + j * 512;
        lut[k] = bf16rne(sinT[k]) | (bf16rne(cosT[k]) << 16);
    }
    ((float2*)accL)[tid] = make_float2(0.f, 0.f);
    __syncthreads();

    float accC[8], accS[8];
#pragma unroll
    for (int t = 0; t < 8; ++t) { accC[t] = 0.f; accS[t] = 0.f; }

    const float4* pAB = packAB + (wv * 64) * NN + ng * 64 + lane;
    const float*  xb  = x + t0 * DM + wv * 64;

#pragma unroll 4
    for (int i = 0; i < NL; ++i) {
        float4 a = pAB[i * NN];      // {invc, bcMagic, attn_cos, attn_sin}
#pragma unroll
        for (int t = 0; t < 8; ++t) {
            float xv = xb[t * DM + i];                 // wave-uniform s_load
            float f  = fmaf(xv, a.x, a.y);             // RNE idx in low mantissa
            unsigned u = lut[__float_as_uint(f) & 4095u];
            float cs = __uint_as_float(u & 0xffff0000u);
            float sn = __uint_as_float(u << 16);
            accC[t] = fmaf(cs, a.z, accC[t]);
            accS[t] = fmaf(sn, a.w, accS[t]);
        }
    }
#pragma unroll 2
    for (int i = NL; i < 64; ++i) {
        float4 a = pAB[i * NN];
#pragma unroll
        for (int t = 0; t < 8; ++t) {
            float xv = xb[t * DM + i];
            float f  = fmaf(xv, a.x, a.y);
            float J  = f - MAGIC;                      // RNE(theta*SCALE), exact
            float ph = __builtin_amdgcn_fractf(J * (1.0f / 4096.0f));
            accC[t] = fmaf(__builtin_amdgcn_cosf(ph), a.z, accC[t]);
            accS[t] = fmaf(__builtin_amdgcn_sinf(ph), a.w, accS[t]);
        }
    }

#pragma unroll
    for (int t = 0; t < 8; ++t) {
        atomicAdd(&accL[t][lane].x, accC[t]);          // ds_add_f32
        atomicAdd(&accL[t][lane].y, accS[t]);
    }
    __syncthreads();
    {
        int t = tid >> 6, n = tid & 63;
        float2 v = accL[t][n];
        pairs[(t0 + t) * NN + ng * 64 + n] = v;
    }
}

// ---------------------------------------------------------------------------
// kproj: out[t][d] = silu( sum_n cs[t][n]*pc[d][n] + ss[t][n]*ps[d][n] )
// Block = 512 thr = 8 waves: 32 d-quads x 8 tokens x 2 n-halves.
// Grid = 128 token-tiles x 4 d-groups. pairs staged in LDS; projT streamed
// from L2; n-half partials combined in LDS.
// ---------------------------------------------------------------------------
__global__ __launch_bounds__(512) void kproj(
    const float2* __restrict__ pairs, const float2* __restrict__ projT,
    float* __restrict__ out)
{
    __shared__ float2 pl[8][NN];     // 32 KB: 8 tokens x 512 neurons
    __shared__ float4 part[512];     // 8 KB partials
    const int bid  = blockIdx.x;     // 512
    const int tile = bid >> 2, dg = bid & 3;
    const int tid  = threadIdx.x;
    const int dslot = tid & 31;
    const int tg   = (tid >> 5) & 7;
    const int nh   = tid >> 8;       // n-half 0/1
    const int t0   = tile * 8;

    {
        const float4* src = (const float4*)(pairs + t0 * NN);
        float4* dst = (float4*)pl;
#pragma unroll
        for (int k = 0; k < 4; ++k) dst[tid + k * 512] = src[tid + k * 512];
    }
    __syncthreads();

    const int gslot = dg * 32 + dslot;                     // global d-quad
    const float4* pp = (const float4*)projT + gslot * 2 + nh * (256 * 256);
    const float2* pt = &pl[tg][nh * 256];
    float4 acc = make_float4(0.f, 0.f, 0.f, 0.f);
#pragma unroll 4
    for (int n = 0; n < 256; ++n) {
        float4 q0 = pp[n * 256];         // {c[d0],s[d0],c[d1],s[d1]}
        float4 q1 = pp[n * 256 + 1];     // {c[d2],s[d2],c[d3],s[d3]}
        float2 cs = pt[n];
        acc.x = fmaf(q0.x, cs.x, acc.x); acc.x = fmaf(q0.y, cs.y, acc.x);
        acc.y = fmaf(q0.z, cs.x, acc.y); acc.y = fmaf(q0.w, cs.y, acc.y);
        acc.z = fmaf(q1.x, cs.x, acc.z); acc.z = fmaf(q1.y, cs.y, acc.z);
        acc.w = fmaf(q1.z, cs.x, acc.w); acc.w = fmaf(q1.w, cs.y, acc.w);
    }
    part[tid] = acc;
    __syncthreads();
    if (tid < 256) {
        float4 a = part[tid], b = part[tid + 256];
        float4 s = make_float4(a.x + b.x, a.y + b.y, a.z + b.z, a.w + b.w);
        float4 o;
        o.x = s.x / (1.f + __expf(-s.x));
        o.y = s.y / (1.f + __expf(-s.y));
        o.z = s.z / (1.f + __expf(-s.z));
        o.w = s.w / (1.f + __expf(-s.w));
        // tid<256 -> nh==0 thread owns (tg, dslot) uniquely
        *(float4*)(out + (t0 + tg) * DM + gslot * 4) = o;
    }
}

// ---------------------------------------------------------------------------
extern "C" void kernel_launch(void* const* d_in, const int* in_sizes, int n_in,
                              void* d_out, int out_size, void* d_ws, size_t ws_size,
                              hipStream_t stream)
{
    const float* x    = (const float*)d_in[0];
    const float* W    = (const float*)d_in[1];
    const float* B    = (const float*)d_in[2];
    const float* AC   = (const float*)d_in[3];
    const float* AS   = (const float*)d_in[4];
    const float* PC   = (const float*)d_in[5];
    const float* PS   = (const float*)d_in[6];
    const float* sinT = (const float*)d_in[7];
    const float* cosT = (const float*)d_in[8];
    float* out = (float*)d_out;

    char* ws = (char*)d_ws;
    float2* packAB = (float2*)ws;                  // 4 MiB [d][n] float4 as 2x float2
    float2* projT  = (float2*)(ws + (4u << 20));   // 2 MiB [n][d] {pc, ps}
    float2* pairs  = (float2*)(ws + (6u << 20));   // 4 MiB [token][n] {cs, ss}

    kprep<<<192, 256, 0, stream>>>(W, B, AC, AS, PC, PS, packAB, projT);
    kmain<<<1024, 512, 0, stream>>>(x, sinT, cosT, (const float4*)packAB, pairs);
    kproj<<<512, 512, 0, stream>>>(pairs, projT, out);
}

// Round 9
// 198.230 us; speedup vs baseline: 1.1420x; 1.1420x over previous
//
#include <hip/hip_runtime.h>
#include <math.h>

#define DM 512
#define NN 512
#define SCALE 651.8986469044033f   // 4096/(2*pi), rounds to same f32 as reference
#define MAGIC 12582912.0f          // 1.5 * 2^23: fma+magic => RNE integer in low mantissa

__device__ __forceinline__ unsigned bf16rne(float f) {
    unsigned u = __float_as_uint(f);
    return (u + 0x7fffu + ((u >> 16) & 1u)) >> 16;
}

// ---------------------------------------------------------------------------
// kprep: 128 blocks = 64 tiles x {packAB, projTb}. One 64x64 transpose each,
// single __syncthreads, all global reads/writes coalesced.
//   mode 0: packAB[d][n] = float4{SCALE/(1+|W|), B*SCALE+MAGIC, attn_cos, attn_sin}
//   mode 1: projTb[n][d] = u32{bf16(pc) | bf16(ps)<<16}
// ---------------------------------------------------------------------------
__global__ __launch_bounds__(256) void kprep(
    const float* __restrict__ W, const float* __restrict__ B,
    const float* __restrict__ AC, const float* __restrict__ AS,
    const float* __restrict__ PC, const float* __restrict__ PS,
    float4* __restrict__ packAB, unsigned* __restrict__ projTb)
{
    __shared__ float4 tile4[64][65];
    const int tid = threadIdx.x;
    const int tx = tid & 63, ty = tid >> 6;
    const int mode = blockIdx.x >> 6;
    const int tl = blockIdx.x & 63;
    const int r0 = (tl >> 3) * 64;
    const int c0 = (tl & 7) * 64;

    if (mode == 0) {
#pragma unroll
        for (int p = 0; p < 16; ++p) {
            int r = p * 4 + ty;
            int src = (r0 + r) * DM + c0 + tx;
            float w = W[src], b = B[src];
            tile4[r][tx] = make_float4(SCALE / (1.0f + fabsf(w)),
                                       fmaf(b, SCALE, MAGIC), AC[src], AS[src]);
        }
        __syncthreads();
#pragma unroll
        for (int p = 0; p < 16; ++p) {
            int c = p * 4 + ty;
            packAB[(c0 + c) * NN + r0 + tx] = tile4[tx][c];
        }
    } else {
        float2* t2 = (float2*)tile4;
#pragma unroll
        for (int p = 0; p < 16; ++p) {
            int r = p * 4 + ty;
            int src = (r0 + r) * NN + c0 + tx;   // PC/PS are [d][n]
            t2[r * 65 + tx] = make_float2(PC[src], PS[src]);
        }
        __syncthreads();
#pragma unroll
        for (int p = 0; p < 16; ++p) {
            int c = p * 4 + ty;
            float2 v = t2[tx * 65 + c];
            projTb[(c0 + c) * DM + r0 + tx] = bf16rne(v.x) | (bf16rne(v.y) << 16);
        }
    }
}

// ---------------------------------------------------------------------------
// kmain: cos_sum/sin_sum over d. Block = 512 thr = 8 waves; block owns
// (8 tokens) x (64 neurons); wave owns a 64-wide d-slice; lane = neuron.
// Grid = 128 token-tiles x 8 ng. x-tile staged TRANSPOSED in LDS (xT[d][t]):
// per d-iter, 2 wave-uniform ds_read_b128 broadcasts fetch all 8 token values
// -> NO s_loads in the hot loop (s_load results force lgkmcnt(0) which drains
// pending ds_read gathers; pure-DS lgkmcnt waits stay fine-grained).
// LUT index = RNE(theta*SCALE) in low mantissa via 1.5*2^23 magic, & 4095.
// ---------------------------------------------------------------------------
__global__ __launch_bounds__(512, 8) void kmain(
    const float* __restrict__ x,
    const float* __restrict__ sinT, const float* __restrict__ cosT,
    const float4* __restrict__ packAB,
    float2* __restrict__ pairs)
{
    __shared__ unsigned lut[4096];   // 16 KB: sin bf16 lo | cos bf16 hi
    __shared__ float xT[512][8];     // 16 KB: x-tile transposed, 32B rows
    __shared__ float2 accL[8][64];   // 4 KB accumulator

    const int tid  = threadIdx.x;
    const int bid  = blockIdx.x;     // 1024 = 128 tiles * 8 ng
    const int tile = bid >> 3, ng = bid & 7;
    const int lane = tid & 63;
    const int wv   = __builtin_amdgcn_readfirstlane(tid >> 6);
    const int t0   = tile * 8;

#pragma unroll
    for (int j = 0; j < 8; ++j) {
        int k = tid + j * 512;
        lut[k] = bf16rne(sinT[k]) | (bf16rne(cosT[k]) << 16);
    }
    // stage x transposed: thread (tt = tid&7, dr = tid>>3) -> 8 d-chunks.
    // LDS write banks: (dr*8 + tt) % 32 = tid % 32 -> 2-way (free).
    {
        const int tt = tid & 7, dr = tid >> 3;
#pragma unroll
        for (int c = 0; c < 8; ++c) {
            int d = c * 64 + dr;
            xT[d][tt] = x[(t0 + tt) * DM + d];
        }
    }
    ((float2*)accL)[tid] = make_float2(0.f, 0.f);
    __syncthreads();

    float accC[8], accS[8];
#pragma unroll
    for (int t = 0; t < 8; ++t) { accC[t] = 0.f; accS[t] = 0.f; }

    const float4* pAB = packAB + (wv * 64) * NN + ng * 64 + lane;

#pragma unroll 2
    for (int i = 0; i < 64; ++i) {
        float4 a = pAB[i * NN];      // {invc, bcMagic, attn_cos, attn_sin}
        const float4* xr = (const float4*)&xT[wv * 64 + i][0];
        float4 xq0 = xr[0], xq1 = xr[1];     // wave-uniform broadcasts
        float xv[8] = {xq0.x, xq0.y, xq0.z, xq0.w, xq1.x, xq1.y, xq1.z, xq1.w};
#pragma unroll
        for (int t = 0; t < 8; ++t) {
            float f  = fmaf(xv[t], a.x, a.y);          // RNE idx in low mantissa
            unsigned u = lut[__float_as_uint(f) & 4095u];
            accC[t] = fmaf(__uint_as_float(u & 0xffff0000u), a.z, accC[t]);
            accS[t] = fmaf(__uint_as_float(u << 16),         a.w, accS[t]);
        }
    }

#pragma unroll
    for (int t = 0; t < 8; ++t) {
        atomicAdd(&accL[t][lane].x, accC[t]);          // ds_add_f32
        atomicAdd(&accL[t][lane].y, accS[t]);
    }
    __syncthreads();
    {
        int t = tid >> 6, n = tid & 63;
        float2 v = accL[t][n];
        pairs[(t0 + t) * NN + ng * 64 + n] = v;
    }
}

// ---------------------------------------------------------------------------
// kproj: out[t][d] = silu( sum_n cs[t][n]*pc[d][n] + ss[t][n]*ps[d][n] )
// Block = 512 thr: 32 d-quads x 8 tokens x 2 n-halves; grid = 128 tiles x 4 dg.
// projTb is bf16-packed {pc,ps} -> one dwordx4 per (thread, n): half the
// VMEM-issue of fp32. pairs staged in LDS; n-half partials combined in LDS.
// ---------------------------------------------------------------------------
__global__ __launch_bounds__(512) void kproj(
    const float2* __restrict__ pairs, const uint4* __restrict__ projTb,
    float* __restrict__ out)
{
    __shared__ float2 pl[8][NN];     // 32 KB
    __shared__ float4 part[512];     // 8 KB
    const int bid  = blockIdx.x;     // 512
    const int tile = bid >> 2, dg = bid & 3;
    const int tid  = threadIdx.x;
    const int dslot = tid & 31;
    const int tg   = (tid >> 5) & 7;
    const int nh   = tid >> 8;       // n-half 0/1
    const int t0   = tile * 8;

    {
        const float4* src = (const float4*)(pairs + t0 * NN);
        float4* dst = (float4*)pl;
#pragma unroll
        for (int k = 0; k < 4; ++k) dst[tid + k * 512] = src[tid + k * 512];
    }
    __syncthreads();

    const int gslot = dg * 32 + dslot;                 // global d-quad 0..127
    const uint4* pp = projTb + nh * (256 * 128) + gslot;
    const float2* pt = &pl[tg][nh * 256];
    float4 acc = make_float4(0.f, 0.f, 0.f, 0.f);
#pragma unroll 4
    for (int n = 0; n < 256; ++n) {
        uint4 q = pp[n * 128];       // 4x u32 {pc_bf16 lo, ps_bf16 hi}
        float2 cs = pt[n];
        acc.x = fmaf(__uint_as_float(q.x << 16), cs.x, acc.x);
        acc.x = fmaf(__uint_as_float(q.x & 0xffff0000u), cs.y, acc.x);
        acc.y = fmaf(__uint_as_float(q.y << 16), cs.x, acc.y);
        acc.y = fmaf(__uint_as_float(q.y & 0xffff0000u), cs.y, acc.y);
        acc.z = fmaf(__uint_as_float(q.z << 16), cs.x, acc.z);
        acc.z = fmaf(__uint_as_float(q.z & 0xffff0000u), cs.y, acc.z);
        acc.w = fmaf(__uint_as_float(q.w << 16), cs.x, acc.w);
        acc.w = fmaf(__uint_as_float(q.w & 0xffff0000u), cs.y, acc.w);
    }
    part[tid] = acc;
    __syncthreads();
    if (tid < 256) {
        float4 a = part[tid], b = part[tid + 256];
        float4 s = make_float4(a.x + b.x, a.y + b.y, a.z + b.z, a.w + b.w);
        float4 o;
        o.x = s.x / (1.f + __expf(-s.x));
        o.y = s.y / (1.f + __expf(-s.y));
        o.z = s.z / (1.f + __expf(-s.z));
        o.w = s.w / (1.f + __expf(-s.w));
        *(float4*)(out + (t0 + tg) * DM + gslot * 4) = o;
    }
}

// ---------------------------------------------------------------------------
extern "C" void kernel_launch(void* const* d_in, const int* in_sizes, int n_in,
                              void* d_out, int out_size, void* d_ws, size_t ws_size,
                              hipStream_t stream)
{
    const float* x    = (const float*)d_in[0];
    const float* W    = (const float*)d_in[1];
    const float* B    = (const float*)d_in[2];
    const float* AC   = (const float*)d_in[3];
    const float* AS   = (const float*)d_in[4];
    const float* PC   = (const float*)d_in[5];
    const float* PS   = (const float*)d_in[6];
    const float* sinT = (const float*)d_in[7];
    const float* cosT = (const float*)d_in[8];
    float* out = (float*)d_out;

    char* ws = (char*)d_ws;
    float4*   packAB = (float4*)ws;                  // 4 MiB [d][n]
    unsigned* projTb = (unsigned*)(ws + (4u << 20)); // 1 MiB [n][d] bf16x2
    float2*   pairs  = (float2*)(ws + (6u << 20));   // 4 MiB [token][n]

    kprep<<<128, 256, 0, stream>>>(W, B, AC, AS, PC, PS, packAB, projTb);
    kmain<<<1024, 512, 0, stream>>>(x, sinT, cosT, packAB, pairs);
    kproj<<<512, 512, 0, stream>>>(pairs, (const uint4*)projTb, out);
}

// Round 11
// 179.105 us; speedup vs baseline: 1.2640x; 1.1068x over previous
//
#include <hip/hip_runtime.h>
#include <math.h>

#define DM 512
#define NN 512
#define SCALE 651.8986469044033f   // 4096/(2*pi), rounds to same f32 as reference
#define MAGIC 12582912.0f          // 1.5 * 2^23: fma+magic => RNE integer in low mantissa
#define INV2PI 0.15915494309189535f
#define NLW 5                      // waves 0..4 = LUT path; waves 5..7 = trans path
#define DSPLIT (NLW * 64)          // d < 320 -> LUT constants, d >= 320 -> trans constants

typedef __attribute__((ext_vector_type(8))) short short8v;
typedef __attribute__((ext_vector_type(4))) float f32x4;

__device__ __forceinline__ unsigned bf16rne(float f) {
    unsigned u = __float_as_uint(f);
    return (u + 0x7fffu + ((u >> 16) & 1u)) >> 16;
}

// ---------------------------------------------------------------------------
// kprep: 128 blocks.
//  mode 0 (64 tiles): LDS-transpose W,B,AC,AS -> packAB[d][n] float4.
//    d < DSPLIT:  {SCALE/(1+|W|),  B*SCALE+MAGIC, ac, as}   (LUT-index form)
//    d >= DSPLIT: {INV2PI/(1+|W|), B*INV2PI,      ac, as}   (revolutions form)
//  mode 1 (64 tiles): direct pack (no transpose): projTb[d][n] = {bf16(pc)|bf16(ps)<<16}
//    = B-operand Bt[d][k] bf16 with k=2n (pc) / 2n+1 (ps).
// ---------------------------------------------------------------------------
__global__ __launch_bounds__(256) void kprep(
    const float* __restrict__ W, const float* __restrict__ B,
    const float* __restrict__ AC, const float* __restrict__ AS,
    const float* __restrict__ PC, const float* __restrict__ PS,
    float4* __restrict__ packAB, unsigned* __restrict__ projTb)
{
    __shared__ float4 tile4[64][65];
    const int tid = threadIdx.x;
    const int tx = tid & 63, ty = tid >> 6;
    const int mode = blockIdx.x >> 6;
    const int tl = blockIdx.x & 63;
    const int r0 = (tl >> 3) * 64;
    const int c0 = (tl & 7) * 64;

    if (mode == 0) {
        const int d = c0 + tx;               // source col = d
#pragma unroll
        for (int p = 0; p < 16; ++p) {
            int r = p * 4 + ty;
            int src = (r0 + r) * DM + d;     // row = n
            float w = W[src], b = B[src];
            float iw = 1.0f + fabsf(w);
            float4 v;
            if (d < DSPLIT)
                v = make_float4(SCALE / iw, fmaf(b, SCALE, MAGIC), AC[src], AS[src]);
            else
                v = make_float4(INV2PI / iw, b * INV2PI, AC[src], AS[src]);
            tile4[r][tx] = v;
        }
        __syncthreads();
#pragma unroll
        for (int p = 0; p < 16; ++p) {
            int c = p * 4 + ty;
            packAB[(c0 + c) * NN + r0 + tx] = tile4[tx][c];
        }
    } else {
        // PC/PS are [d][n]; same layout out -> fully coalesced, no LDS
#pragma unroll
        for (int p = 0; p < 16; ++p) {
            int r = p * 4 + ty;
            int src = (r0 + r) * NN + c0 + tx;
            projTb[src] = bf16rne(PC[src]) | (bf16rne(PS[src]) << 16);
        }
    }
}

// ---------------------------------------------------------------------------
// kmain: wave-specialized. Block = 512 thr = 8 waves; block owns (8 tok)x(64 n);
// wave wv owns d-slice [wv*64, +64). Waves 0..4: LDS-LUT gather path (LDS pipe).
// Waves 5..7: v_sin/v_cos path (trans pipe). Both pipes run CONCURRENTLY on the
// CU. x staged transposed in LDS; cross-wave reduce via ds_add_f32; output
// packed to bf16 pairs (A-operand for the MFMA projection).
// ---------------------------------------------------------------------------
__global__ __launch_bounds__(512, 8) void kmain(
    const float* __restrict__ x,
    const float* __restrict__ sinT, const float* __restrict__ cosT,
    const float4* __restrict__ packAB,
    unsigned* __restrict__ pairsb)
{
    __shared__ unsigned lut[4096];   // 16 KB: sin bf16 lo | cos bf16 hi
    __shared__ float xT[512][8];     // 16 KB: x-tile transposed
    __shared__ float2 accL[8][64];   // 4 KB accumulator

    const int tid  = threadIdx.x;
    const int bid  = blockIdx.x;     // 1024 = 128 tiles * 8 ng
    const int tile = bid >> 3, ng = bid & 7;
    const int lane = tid & 63;
    const int wv   = __builtin_amdgcn_readfirstlane(tid >> 6);
    const int t0   = tile * 8;

#pragma unroll
    for (int j = 0; j < 8; ++j) {
        int k = tid + j * 512;
        lut[k] = bf16rne(sinT[k]) | (bf16rne(cosT[k]) << 16);
    }
    {
        const int tt = tid & 7, dr = tid >> 3;
#pragma unroll
        for (int c = 0; c < 8; ++c) {
            int d = c * 64 + dr;
            xT[d][tt] = x[(t0 + tt) * DM + d];
        }
    }
    ((float2*)accL)[tid] = make_float2(0.f, 0.f);
    __syncthreads();

    float accC[8], accS[8];
#pragma unroll
    for (int t = 0; t < 8; ++t) { accC[t] = 0.f; accS[t] = 0.f; }

    const float4* pAB = packAB + (wv * 64) * NN + ng * 64 + lane;

    if (wv < NLW) {
        // ---- LUT path: 1 random b32 LDS gather per element
#pragma unroll 2
        for (int i = 0; i < 64; ++i) {
            float4 a = pAB[i * NN];      // {invc, bcMagic, ac, as}
            const float4* xr = (const float4*)&xT[wv * 64 + i][0];
            float4 xq0 = xr[0], xq1 = xr[1];
            float xv[8] = {xq0.x, xq0.y, xq0.z, xq0.w, xq1.x, xq1.y, xq1.z, xq1.w};
#pragma unroll
            for (int t = 0; t < 8; ++t) {
                float f  = fmaf(xv[t], a.x, a.y);      // RNE idx in low mantissa
                unsigned u = lut[__float_as_uint(f) & 4095u];
                accC[t] = fmaf(__uint_as_float(u & 0xffff0000u), a.z, accC[t]);
                accS[t] = fmaf(__uint_as_float(u << 16),         a.w, accS[t]);
            }
        }
    } else {
        // ---- trans path: v_sin/v_cos in revolutions (no LDS traffic)
#pragma unroll 2
        for (int i = 0; i < 64; ++i) {
            float4 a = pAB[i * NN];      // {inv2pi_w, b/2pi, ac, as}
            const float4* xr = (const float4*)&xT[wv * 64 + i][0];
            float4 xq0 = xr[0], xq1 = xr[1];
            float xv[8] = {xq0.x, xq0.y, xq0.z, xq0.w, xq1.x, xq1.y, xq1.z, xq1.w};
#pragma unroll
            for (int t = 0; t < 8; ++t) {
                float ph = __builtin_amdgcn_fractf(fmaf(xv[t], a.x, a.y));
                accC[t] = fmaf(__builtin_amdgcn_cosf(ph), a.z, accC[t]);
                accS[t] = fmaf(__builtin_amdgcn_sinf(ph), a.w, accS[t]);
            }
        }
    }

#pragma unroll
    for (int t = 0; t < 8; ++t) {
        atomicAdd(&accL[t][lane].x, accC[t]);          // ds_add_f32
        atomicAdd(&accL[t][lane].y, accS[t]);
    }
    __syncthreads();
    {
        int t = tid >> 6, n = tid & 63;
        float2 v = accL[t][n];
        pairsb[(t0 + t) * NN + ng * 64 + n] = bf16rne(v.x) | (bf16rne(v.y) << 16);
    }
}

// ---------------------------------------------------------------------------
// kproj: out = silu( A[1024 x 1024k] * B[1024k x 512] ), k = {cos,sin}
// interleaved over n. MFMA 16x16x32 bf16, fp32 accumulate.
// A = pairsb ([t][k] bf16), B = projTb ([d][k] bf16 = B-cols row-major).
// Fragment layouts (m89-verified C/D; standard A/B):
//   A: lane l -> row m = l&15, k = (l>>4)*8 + j
//   B: lane l -> col d = l&15, k = (l>>4)*8 + j
//   D: lane l, reg r -> col d = l&15, row m = (l>>4)*4 + r
// Grid = 512 blocks x 256 thr (4 waves); wave owns one 16x16 out tile.
// ---------------------------------------------------------------------------
__global__ __launch_bounds__(256) void kproj(
    const unsigned* __restrict__ pairsb, const unsigned* __restrict__ projTb,
    float* __restrict__ out)
{
    const int tid  = threadIdx.x;
    const int lane = tid & 63;
    const int w    = tid >> 6;
    const int tileIdx = blockIdx.x * 4 + w;      // 0..2047
    const int tt = tileIdx >> 5;                 // t-tile 0..63
    const int dt = tileIdx & 31;                 // d-tile 0..31
    const int r16 = lane & 15;
    const int kg  = lane >> 4;                   // k-group of 8

    const short* Af = (const short*)pairsb;      // bf16 [1024][1024]
    const short* Bf = (const short*)projTb;      // bf16 [512][1024]
    const short8v* pa = (const short8v*)(Af + (tt * 16 + r16) * 1024 + kg * 8);
    const short8v* pb = (const short8v*)(Bf + (dt * 16 + r16) * 1024 + kg * 8);

    f32x4 acc = {0.f, 0.f, 0.f, 0.f};
#pragma unroll 4
    for (int kk = 0; kk < 32; ++kk) {
        short8v a = pa[kk * 4];                  // advance K by 32
        short8v b = pb[kk * 4];
        acc = __builtin_amdgcn_mfma_f32_16x16x32_bf16(a, b, acc, 0, 0, 0);
    }
#pragma unroll
    for (int r = 0; r < 4; ++r) {
        int m = kg * 4 + r;
        float s = acc[r];
        float o = s / (1.f + __expf(-s));
        out[(tt * 16 + m) * DM + dt * 16 + r16] = o;
    }
}

// ---------------------------------------------------------------------------
extern "C" void kernel_launch(void* const* d_in, const int* in_sizes, int n_in,
                              void* d_out, int out_size, void* d_ws, size_t ws_size,
                              hipStream_t stream)
{
    const float* x    = (const float*)d_in[0];
    const float* W    = (const float*)d_in[1];
    const float* B    = (const float*)d_in[2];
    const float* AC   = (const float*)d_in[3];
    const float* AS   = (const float*)d_in[4];
    const float* PC   = (const float*)d_in[5];
    const float* PS   = (const float*)d_in[6];
    const float* sinT = (const float*)d_in[7];
    const float* cosT = (const float*)d_in[8];
    float* out = (float*)d_out;

    char* ws = (char*)d_ws;
    float4*   packAB = (float4*)ws;                  // 4 MiB [d][n]
    unsigned* projTb = (unsigned*)(ws + (4u << 20)); // 1 MiB [d][n] bf16x2 (B-operand)
    unsigned* pairsb = (unsigned*)(ws + (6u << 20)); // 2 MiB [t][n] bf16x2 (A-operand)

    kprep<<<128, 256, 0, stream>>>(W, B, AC, AS, PC, PS, packAB, projTb);
    kmain<<<1024, 512, 0, stream>>>(x, sinT, cosT, packAB, pairsb);
    kproj<<<512, 256, 0, stream>>>(pairsb, projTb, out);
}

// Round 12
// 170.473 us; speedup vs baseline: 1.3280x; 1.0506x over previous
//
#include <hip/hip_runtime.h>
#include <math.h>

#define DM 512
#define NN 512
#define SCALE 651.8986469044033f   // 4096/(2*pi), rounds to same f32 as reference
#define MAGIC 12582912.0f          // 1.5 * 2^23: fma+magic => RNE integer in low mantissa
#define INV2PI 0.15915494309189535f
#define NLW 5                      // waves 0..4 = LUT path; waves 5..7 = trans path
#define DSPLIT (NLW * 64)          // d < 320 -> LUT constants, d >= 320 -> trans constants

typedef __attribute__((ext_vector_type(8))) short short8v;
typedef __attribute__((ext_vector_type(4))) float f32x4;

__device__ __forceinline__ unsigned bf16rne(float f) {
    unsigned u = __float_as_uint(f);
    return (u + 0x7fffu + ((u >> 16) & 1u)) >> 16;
}

// Fragment address for MFMA 16x16x32 bf16 operands, u32 granularity.
// Operand rows (A: t, B: d) tile by 16; k = 2n + {0=cos,1=sin}.
// lane l = (row&15) + 16*q, q = (n>>2)&3; u32 slot s = n&3; kk = n>>4.
__device__ __forceinline__ int frag_idx(int row, int n) {
    int rt = row >> 4, m = row & 15;
    int kk = n >> 4, q = (n >> 2) & 3, s = n & 3;
    return ((rt * 32 + kk) * 64 + m + 16 * q) * 4 + s;
}

// ---------------------------------------------------------------------------
// kprep: 128 blocks.
//  mode 0 (64 tiles): LDS-transpose W,B,AC,AS -> packAB[d][n] float4.
//    d < DSPLIT:  {SCALE/(1+|W|),  B*SCALE+MAGIC, ac, as}   (LUT-index form)
//    d >= DSPLIT: {INV2PI/(1+|W|), B*INV2PI,      ac, as}   (revolutions form)
//  mode 1 (64 tiles): pack PC/PS into the MFMA B-fragment layout (bfrag).
// ---------------------------------------------------------------------------
__global__ __launch_bounds__(256) void kprep(
    const float* __restrict__ W, const float* __restrict__ B,
    const float* __restrict__ AC, const float* __restrict__ AS,
    const float* __restrict__ PC, const float* __restrict__ PS,
    float4* __restrict__ packAB, unsigned* __restrict__ bfrag)
{
    __shared__ float4 tile4[64][65];
    const int tid = threadIdx.x;
    const int tx = tid & 63, ty = tid >> 6;
    const int mode = blockIdx.x >> 6;
    const int tl = blockIdx.x & 63;
    const int r0 = (tl >> 3) * 64;
    const int c0 = (tl & 7) * 64;

    if (mode == 0) {
        const int d = c0 + tx;               // source col = d
#pragma unroll
        for (int p = 0; p < 16; ++p) {
            int r = p * 4 + ty;
            int src = (r0 + r) * DM + d;     // row = n
            float w = W[src], b = B[src];
            float iw = 1.0f + fabsf(w);
            float4 v;
            if (d < DSPLIT)
                v = make_float4(SCALE / iw, fmaf(b, SCALE, MAGIC), AC[src], AS[src]);
            else
                v = make_float4(INV2PI / iw, b * INV2PI, AC[src], AS[src]);
            tile4[r][tx] = v;
        }
        __syncthreads();
#pragma unroll
        for (int p = 0; p < 16; ++p) {
            int c = p * 4 + ty;
            packAB[(c0 + c) * NN + r0 + tx] = tile4[tx][c];
        }
    } else {
        // PC/PS are [d][n]: row = d, col = n -> B-fragment layout
#pragma unroll
        for (int p = 0; p < 16; ++p) {
            int r = p * 4 + ty;
            int d = r0 + r, n = c0 + tx;
            int src = d * NN + n;
            bfrag[frag_idx(d, n)] = bf16rne(PC[src]) | (bf16rne(PS[src]) << 16);
        }
    }
}

// ---------------------------------------------------------------------------
// kmain: wave-specialized (unchanged from r11 except epilogue). Block = 512thr
// = 8 waves; block owns (8 tok)x(64 n); wave wv owns d-slice [wv*64,+64).
// Waves 0..4: LDS-LUT gather path. Waves 5..7: v_sin/v_cos trans path.
// Epilogue writes the reduced {cs,sn} bf16 pair directly into the MFMA
// A-fragment layout (afrag) so kproj's loads are fully coalesced.
// ---------------------------------------------------------------------------
__global__ __launch_bounds__(512, 8) void kmain(
    const float* __restrict__ x,
    const float* __restrict__ sinT, const float* __restrict__ cosT,
    const float4* __restrict__ packAB,
    unsigned* __restrict__ afrag)
{
    __shared__ unsigned lut[4096];   // 16 KB: sin bf16 lo | cos bf16 hi
    __shared__ float xT[512][8];     // 16 KB: x-tile transposed
    __shared__ float2 accL[8][64];   // 4 KB accumulator

    const int tid  = threadIdx.x;
    const int bid  = blockIdx.x;     // 1024 = 128 tiles * 8 ng
    const int tile = bid >> 3, ng = bid & 7;
    const int lane = tid & 63;
    const int wv   = __builtin_amdgcn_readfirstlane(tid >> 6);
    const int t0   = tile * 8;

#pragma unroll
    for (int j = 0; j < 8; ++j) {
        int k = tid + j * 512;
        lut[k] = bf16rne(sinT[k]) | (bf16rne(cosT[k]) << 16);
    }
    {
        const int tt = tid & 7, dr = tid >> 3;
#pragma unroll
        for (int c = 0; c < 8; ++c) {
            int d = c * 64 + dr;
            xT[d][tt] = x[(t0 + tt) * DM + d];
        }
    }
    ((float2*)accL)[tid] = make_float2(0.f, 0.f);
    __syncthreads();

    float accC[8], accS[8];
#pragma unroll
    for (int t = 0; t < 8; ++t) { accC[t] = 0.f; accS[t] = 0.f; }

    const float4* pAB = packAB + (wv * 64) * NN + ng * 64 + lane;

    if (wv < NLW) {
        // ---- LUT path: 1 random b32 LDS gather per element
#pragma unroll 2
        for (int i = 0; i < 64; ++i) {
            float4 a = pAB[i * NN];      // {invc, bcMagic, ac, as}
            const float4* xr = (const float4*)&xT[wv * 64 + i][0];
            float4 xq0 = xr[0], xq1 = xr[1];
            float xv[8] = {xq0.x, xq0.y, xq0.z, xq0.w, xq1.x, xq1.y, xq1.z, xq1.w};
#pragma unroll
            for (int t = 0; t < 8; ++t) {
                float f  = fmaf(xv[t], a.x, a.y);      // RNE idx in low mantissa
                unsigned u = lut[__float_as_uint(f) & 4095u];
                accC[t] = fmaf(__uint_as_float(u & 0xffff0000u), a.z, accC[t]);
                accS[t] = fmaf(__uint_as_float(u << 16),         a.w, accS[t]);
            }
        }
    } else {
        // ---- trans path: v_sin/v_cos in revolutions (no LDS traffic)
#pragma unroll 2
        for (int i = 0; i < 64; ++i) {
            float4 a = pAB[i * NN];      // {inv2pi_w, b/2pi, ac, as}
            const float4* xr = (const float4*)&xT[wv * 64 + i][0];
            float4 xq0 = xr[0], xq1 = xr[1];
            float xv[8] = {xq0.x, xq0.y, xq0.z, xq0.w, xq1.x, xq1.y, xq1.z, xq1.w};
#pragma unroll
            for (int t = 0; t < 8; ++t) {
                float ph = __builtin_amdgcn_fractf(fmaf(xv[t], a.x, a.y));
                accC[t] = fmaf(__builtin_amdgcn_cosf(ph), a.z, accC[t]);
                accS[t] = fmaf(__builtin_amdgcn_sinf(ph), a.w, accS[t]);
            }
        }
    }

#pragma unroll
    for (int t = 0; t < 8; ++t) {
        atomicAdd(&accL[t][lane].x, accC[t]);          // ds_add_f32
        atomicAdd(&accL[t][lane].y, accS[t]);
    }
    __syncthreads();
    {
        int t = tid >> 6, n64 = tid & 63;
        float2 v = accL[t][n64];
        afrag[frag_idx(t0 + t, ng * 64 + n64)] =
            bf16rne(v.x) | (bf16rne(v.y) << 16);
    }
}

// ---------------------------------------------------------------------------
// kproj: out = silu( A[1024 x 1024k] * B^T[512 x 1024k] ), k = {cos,sin}
// interleaved over n. Both operands pre-packed in MFMA fragment order:
// frag[rt][kk][lane] 16B -> every load is a fully-coalesced 1 KB dwordx4.
// Grid = 512 blocks x 256 thr (4 waves); wave owns one 16x16 out tile;
// no LDS, no barriers. D layout (m89-verified): col=lane&15, row=(lane>>4)*4+r.
// ---------------------------------------------------------------------------
__global__ __launch_bounds__(256) void kproj(
    const short8v* __restrict__ afrag, const short8v* __restrict__ bfrag,
    float* __restrict__ out)
{
    const int tid  = threadIdx.x;
    const int lane = tid & 63;
    const int w    = tid >> 6;
    const int tileIdx = blockIdx.x * 4 + w;      // 0..2047
    const int tt = tileIdx >> 5;                 // t-tile 0..63
    const int dt = tileIdx & 31;                 // d-tile 0..31

    const short8v* pa = afrag + tt * 32 * 64 + lane;   // + kk*64 per K-step
    const short8v* pb = bfrag + dt * 32 * 64 + lane;

    f32x4 acc = {0.f, 0.f, 0.f, 0.f};
#pragma unroll 8
    for (int kk = 0; kk < 32; ++kk) {
        short8v a = pa[kk * 64];
        short8v b = pb[kk * 64];
        acc = __builtin_amdgcn_mfma_f32_16x16x32_bf16(a, b, acc, 0, 0, 0);
    }
#pragma unroll
    for (int r = 0; r < 4; ++r) {
        int m = (lane >> 4) * 4 + r;
        float s = acc[r];
        float o = s / (1.f + __expf(-s));
        out[(tt * 16 + m) * DM + dt * 16 + (lane & 15)] = o;
    }
}

// ---------------------------------------------------------------------------
extern "C" void kernel_launch(void* const* d_in, const int* in_sizes, int n_in,
                              void* d_out, int out_size, void* d_ws, size_t ws_size,
                              hipStream_t stream)
{
    const float* x    = (const float*)d_in[0];
    const float* W    = (const float*)d_in[1];
    const float* B    = (const float*)d_in[2];
    const float* AC   = (const float*)d_in[3];
    const float* AS   = (const float*)d_in[4];
    const float* PC   = (const float*)d_in[5];
    const float* PS   = (const float*)d_in[6];
    const float* sinT = (const float*)d_in[7];
    const float* cosT = (const float*)d_in[8];
    float* out = (float*)d_out;

    char* ws = (char*)d_ws;
    float4*   packAB = (float4*)ws;                  // 4 MiB [d][n]
    unsigned* bfrag  = (unsigned*)(ws + (4u << 20)); // 1 MiB B-fragments
    unsigned* afrag  = (unsigned*)(ws + (6u << 20)); // 2 MiB A-fragments

    kprep<<<128, 256, 0, stream>>>(W, B, AC, AS, PC, PS, packAB, bfrag);
    kmain<<<1024, 512, 0, stream>>>(x, sinT, cosT, packAB, afrag);
    kproj<<<512, 256, 0, stream>>>((const short8v*)afrag, (const short8v*)bfrag, out);
}